// Round 8
// baseline (2761.362 us; speedup 1.0000x reference)
//
#include <hip/hip_runtime.h>
#include <hip/hip_bf16.h>

// ---- int8 path: per-row dynamic quant of x, exact int8 W, i32 MFMA accum ----
#define BM 256
#define BN 256
#define BK 64          // 64 int8 per row per K-tile
#define NSLOT 2        // double buffer: 64 KiB LDS -> 2 blocks/CU (anti-phase)

typedef float  f32x4  __attribute__((ext_vector_type(4)));
typedef int    i32x4  __attribute__((ext_vector_type(4)));
typedef int    i32x16 __attribute__((ext_vector_type(16)));
typedef __bf16 bf16x8 __attribute__((ext_vector_type(8)));
typedef __bf16 bf16x4 __attribute__((ext_vector_type(4)));

__device__ __forceinline__ void gload_lds16(const void* g, void* l) {
    __builtin_amdgcn_global_load_lds(
        (const __attribute__((address_space(1))) void*)g,
        (__attribute__((address_space(3))) void*)l, 16, 0, 0);
}

// ------------- prepass 1: per-row absmax quant of x -> int8 + scale ----------
__global__ __launch_bounds__(256)
void rowquant_x(const float* __restrict__ x, signed char* __restrict__ xq,
                float* __restrict__ xs, int K) {
    const int row = blockIdx.x;
    const float* xr = x + (size_t)row * K;
    const int tid = threadIdx.x;
    const int n4 = K / 4;

    float mx = 0.f;
    for (int i = tid; i < n4; i += 256) {
        f32x4 v = ((const f32x4*)xr)[i];
        mx = fmaxf(mx, fmaxf(fmaxf(fabsf(v[0]), fabsf(v[1])),
                             fmaxf(fabsf(v[2]), fabsf(v[3]))));
    }
#pragma unroll
    for (int off = 32; off; off >>= 1)
        mx = fmaxf(mx, __shfl_xor(mx, off));
    __shared__ float smx[4];
    if ((tid & 63) == 0) smx[tid >> 6] = mx;
    __syncthreads();
    mx = fmaxf(fmaxf(smx[0], smx[1]), fmaxf(smx[2], smx[3]));

    const float inv = mx > 0.f ? 127.f / mx : 0.f;
    if (tid == 0) xs[row] = mx / 127.f;

    unsigned* out = (unsigned*)(xq + (size_t)row * K);
    for (int i = tid; i < n4; i += 256) {     // re-read: row is cache-resident
        f32x4 v = ((const f32x4*)xr)[i];
        int q0 = __float2int_rn(v[0] * inv);
        int q1 = __float2int_rn(v[1] * inv);
        int q2 = __float2int_rn(v[2] * inv);
        int q3 = __float2int_rn(v[3] * inv);
        out[i] = (unsigned)(q0 & 255) | ((unsigned)(q1 & 255) << 8) |
                 ((unsigned)(q2 & 255) << 16) | ((unsigned)(q3 & 255) << 24);
    }
}

// ------------- prepass 2: pack W int32 -> int8 (exact) -----------------------
__global__ __launch_bounds__(256)
void cvt_w_i8(const int* __restrict__ w, unsigned* __restrict__ wq, int n4) {
    int i = blockIdx.x * 256 + threadIdx.x;
    const int stride = gridDim.x * 256;
    for (; i < n4; i += stride) {
        i32x4 v = ((const i32x4*)w)[i];
        wq[i] = (unsigned)(v[0] & 255) | ((unsigned)(v[1] & 255) << 8) |
                ((unsigned)(v[2] & 255) << 16) | ((unsigned)(v[3] & 255) << 24);
    }
}

// ------------- main GEMM: i8 32x32x32 MFMA, double-buffer, 2 blocks/CU -------
// LDS K-tile slot (per operand): [2 k-steps][256 rows][32 B], 16 KiB.
//   phys(kstep,row,half) = kstep*8192 + row*32 + (half ^ ((row>>3)&1))*16
// 2-way bank pattern on ds_read_b128 (free); conflicts measured 0 (R6).
// gload_lds writes linearly; GLOBAL source carries the inverse swizzle.
//
// Sync design (R8): NSLOT=2 -> 64 KiB LDS -> TWO independent blocks per CU.
// Each tile: vmcnt(0); barrier; STAGE(t+1); 12 ds_reads; 16-MFMA cluster.
// WAR-safety for STAGE(t+1) (slot read at t-1): issued only after barrier t,
// which waves reach only after their t-1 reads were consumed by MFMAs (lgkm
// drained). The vmcnt(0) drain stall is covered by the OTHER resident
// block's compute (m114 cross-block anti-phase overlap) — the point of R8.

__global__ __launch_bounds__(512, 4)
void qlin_gemm_i8(const signed char* __restrict__ A,  // [M,K] int8 x-quant
                  const signed char* __restrict__ B,  // [N,K] int8 w
                  const float* __restrict__ xs,       // [M] x row scales
                  const float* __restrict__ scale,    // [N]
                  const float* __restrict__ bias,     // [N]
                  float* __restrict__ C, int M, int N, int K) {
    extern __shared__ signed char lds[];
    signed char* lA = lds;                       // [NSLOT][16384]
    signed char* lB = lds + NSLOT * (BM * BK);

    const int NTN = N / BN;
    const int nwg = gridDim.x;
    int bid = blockIdx.x;
    bid = (bid & 7) * (nwg >> 3) + (bid >> 3);   // XCD swizzle (nwg%8==0)
    const int tm = bid / NTN;
    const int tn = bid % NTN;

    const int tid  = threadIdx.x;
    const int lane = tid & 63;
    const int wid  = tid >> 6;     // 0..7
    const int wr   = wid >> 2;     // 0..1  (M half: 128 rows)
    const int wc   = wid & 3;      // 0..3  (N quarter: 64 cols)

    // staging map: lane covers row wid*32 + (lane>>1), physical half lane&1
    const int srow  = wid * 32 + (lane >> 1);
    const int shalf = (lane & 1) ^ ((srow >> 3) & 1);   // logical half (inv swz)
    const signed char* Abase = A + (size_t)(tm * BM + srow) * K + shalf * 16;
    const signed char* Bbase = B + (size_t)(tn * BN + srow) * K + shalf * 16;

    const int NT = K / BK;

    auto STAGE_A = [&](int t) {
        signed char* d = lA + (t & (NSLOT - 1)) * (BM * BK) + wid * 1024;
#pragma unroll
        for (int j = 0; j < 2; ++j)   // j = k-step
            gload_lds16(Abase + t * BK + j * 32, d + j * 8192);
    };
    auto STAGE_B = [&](int t) {
        signed char* d = lB + (t & (NSLOT - 1)) * (BM * BK) + wid * 1024;
#pragma unroll
        for (int j = 0; j < 2; ++j)
            gload_lds16(Bbase + t * BK + j * 32, d + j * 8192);
    };

    i32x16 acc[4][2];
#pragma unroll
    for (int mi = 0; mi < 4; ++mi)
#pragma unroll
        for (int ni = 0; ni < 2; ++ni)
#pragma unroll
            for (int r = 0; r < 16; ++r) acc[mi][ni][r] = 0;

    // prologue: stage tile 0 only (double buffer, distance 1)
    STAGE_A(0); STAGE_B(0);

    const int fr = lane & 31;      // M/N row within 32x32 fragment
    const int fh = lane >> 5;      // k-half selector (16 B)
    const int swz = (fr >> 3) & 1; // row-bit3 slot swizzle

    for (int t = 0; t < NT; ++t) {
        const signed char* lAs = lA + (t & (NSLOT - 1)) * (BM * BK);
        const signed char* lBs = lB + (t & (NSLOT - 1)) * (BM * BK);

        asm volatile("s_waitcnt vmcnt(0)" ::: "memory");  // tile t staged
        __builtin_amdgcn_s_barrier();

        // stage NEXT tile into the other slot (WAR-safe: see header comment)
        if (t + 1 < NT) { STAGE_A(t + 1); STAGE_B(t + 1); }

        // ---- all 12 ds_reads upfront (both k-steps) ----
        const int ho0 = ((fh ^ swz) << 4);
        const int ho1 = 8192 + ho0;
        i32x4 af0[4], af1[4], bf0[2], bf1[2];
#pragma unroll
        for (int mi = 0; mi < 4; ++mi) {
            const int R = wr * 128 + mi * 32 + fr;
            af0[mi] = *(const i32x4*)(lAs + R * 32 + ho0);
        }
#pragma unroll
        for (int ni = 0; ni < 2; ++ni) {
            const int R = wc * 64 + ni * 32 + fr;
            bf0[ni] = *(const i32x4*)(lBs + R * 32 + ho0);
        }
#pragma unroll
        for (int mi = 0; mi < 4; ++mi) {
            const int R = wr * 128 + mi * 32 + fr;
            af1[mi] = *(const i32x4*)(lAs + R * 32 + ho1);
        }
#pragma unroll
        for (int ni = 0; ni < 2; ++ni) {
            const int R = wc * 64 + ni * 32 + fr;
            bf1[ni] = *(const i32x4*)(lBs + R * 32 + ho1);
        }

        // ---- single 16-MFMA cluster ----
        __builtin_amdgcn_s_setprio(1);
#pragma unroll
        for (int mi = 0; mi < 4; ++mi)
#pragma unroll
            for (int ni = 0; ni < 2; ++ni)
                acc[mi][ni] = __builtin_amdgcn_mfma_i32_32x32x32_i8(
                    af0[mi], bf0[ni], acc[mi][ni], 0, 0, 0);
#pragma unroll
        for (int mi = 0; mi < 4; ++mi)
#pragma unroll
            for (int ni = 0; ni < 2; ++ni)
                acc[mi][ni] = __builtin_amdgcn_mfma_i32_32x32x32_i8(
                    af1[mi], bf1[ni], acc[mi][ni], 0, 0, 0);
        __builtin_amdgcn_s_setprio(0);
    }

    // epilogue: 32x32 C/D layout: col = lane&31, row = (r&3)+8*(r>>2)+4*(lane>>5)
    const int rb = tm * BM + wr * 128 + 4 * fh;
    const int cb = tn * BN + wc * 64 + fr;
#pragma unroll
    for (int mi = 0; mi < 4; ++mi) {
        float sm[16];
#pragma unroll
        for (int r = 0; r < 16; ++r)
            sm[r] = xs[rb + mi * 32 + (r & 3) + 8 * (r >> 2)];
#pragma unroll
        for (int ni = 0; ni < 2; ++ni) {
            const int n = cb + ni * 32;
            const float sc = scale[n];
            const float bs = bias[n];
#pragma unroll
            for (int r = 0; r < 16; ++r) {
                const int m = rb + mi * 32 + (r & 3) + 8 * (r >> 2);
                C[(size_t)m * N + n] = fmaf((float)acc[mi][ni][r], sm[r] * sc, bs);
            }
        }
    }
}

// ---------------- fallback (reg-staged 128^2 bf16, any shape) ----------------
#define FBM 128
#define FBK 32

__device__ __forceinline__ int swz_elem(int row, int e) {
    return row * FBK + (e ^ (((row >> 1) & 3) << 3));
}

__global__ __launch_bounds__(256, 2)
void qlin_gemm_reg(const float* __restrict__ A, const int* __restrict__ W,
                   const float* __restrict__ scale, const float* __restrict__ bias,
                   float* __restrict__ C, int M, int N, int K) {
    __shared__ __bf16 lA[2][FBM * FBK];
    __shared__ __bf16 lB[2][FBM * FBK];
    const int NTN = N / FBM;
    const int nwg = gridDim.x;
    int bid = blockIdx.x;
    if ((nwg & 7) == 0) bid = (bid & 7) * (nwg >> 3) + (bid >> 3);
    const int tm = bid / NTN, tn = bid % NTN;
    const int tid = threadIdx.x, lane = tid & 63, wid = tid >> 6;
    const int wr = wid >> 1, wc = wid & 1;
    const int srow0 = tid >> 3, skq = tid & 7;
    const float* aptr = A + (size_t)(tm * FBM + srow0) * K + skq * 4;
    const int*   wptr = W + (size_t)(tn * FBM + srow0) * K + skq * 4;
    const size_t rstride = (size_t)32 * K;
    f32x4 sa[4]; i32x4 sw[4];
    auto LOAD = [&](int t) {
#pragma unroll
        for (int j = 0; j < 4; ++j) {
            sa[j] = *(const f32x4*)(aptr + (size_t)t * FBK + j * rstride);
            sw[j] = *(const i32x4*)(wptr + (size_t)t * FBK + j * rstride);
        }
    };
    auto STORE = [&](int buf) {
#pragma unroll
        for (int j = 0; j < 4; ++j) {
            const int idx = swz_elem(srow0 + j * 32, skq * 4);
            bf16x4 va = { (__bf16)sa[j][0], (__bf16)sa[j][1],
                          (__bf16)sa[j][2], (__bf16)sa[j][3] };
            bf16x4 vw = { (__bf16)(float)sw[j][0], (__bf16)(float)sw[j][1],
                          (__bf16)(float)sw[j][2], (__bf16)(float)sw[j][3] };
            *(bf16x4*)&lA[buf][idx] = va;
            *(bf16x4*)&lB[buf][idx] = vw;
        }
    };
    const f32x4 fzero = {0.f, 0.f, 0.f, 0.f};
    f32x4 acc[4][4];
#pragma unroll
    for (int i = 0; i < 4; ++i)
#pragma unroll
        for (int j = 0; j < 4; ++j) acc[i][j] = fzero;
    const int fr = lane & 15, fks = (lane >> 4) * 8;
    LOAD(0); STORE(0); __syncthreads();
    const int NT = K / FBK;
    for (int t = 0; t < NT; ++t) {
        const int buf = t & 1;
        if (t + 1 < NT) LOAD(t + 1);
        bf16x8 af[4], bfg[4];
#pragma unroll
        for (int mi = 0; mi < 4; ++mi)
            af[mi] = *(const bf16x8*)&lA[buf][swz_elem(wr * 64 + mi * 16 + fr, fks)];
#pragma unroll
        for (int ni = 0; ni < 4; ++ni)
            bfg[ni] = *(const bf16x8*)&lB[buf][swz_elem(wc * 64 + ni * 16 + fr, fks)];
#pragma unroll
        for (int mi = 0; mi < 4; ++mi)
#pragma unroll
            for (int ni = 0; ni < 4; ++ni)
                acc[mi][ni] = __builtin_amdgcn_mfma_f32_16x16x32_bf16(
                    af[mi], bfg[ni], acc[mi][ni], 0, 0, 0);
        if (t + 1 < NT) STORE(buf ^ 1);
        __syncthreads();
    }
    const int row0 = tm * FBM + wr * 64 + (lane >> 4) * 4;
    const int col0 = tn * FBM + wc * 64 + fr;
#pragma unroll
    for (int ni = 0; ni < 4; ++ni) {
        const int n = col0 + ni * 16;
        const float sc = scale[n], bs = bias[n];
#pragma unroll
        for (int mi = 0; mi < 4; ++mi) {
            const int m = row0 + mi * 16;
#pragma unroll
            for (int r = 0; r < 4; ++r)
                C[(size_t)(m + r) * N + n] = fmaf(acc[mi][ni][r], sc, bs);
        }
    }
}

extern "C" void kernel_launch(void* const* d_in, const int* in_sizes, int n_in,
                              void* d_out, int out_size, void* d_ws, size_t ws_size,
                              hipStream_t stream) {
    const float* x     = (const float*)d_in[0];
    const int*   w8    = (const int*)d_in[1];
    const float* scale = (const float*)d_in[2];
    const float* bias  = (const float*)d_in[3];
    float*       out   = (float*)d_out;

    const int DOUT = in_sizes[2];
    const int DIN  = in_sizes[1] / DOUT;
    const int M    = in_sizes[0] / DIN;

    const size_t need = (size_t)M * DIN + (size_t)DOUT * DIN + (size_t)M * 4;
    const int nwg = (M / BM) * (DOUT / BN);
    const bool ok = (ws_size >= need) && (M % BM == 0) && (DOUT % BN == 0) &&
                    (DIN % BK == 0) && (nwg % 8 == 0) && (DIN / BK >= 2);
    if (ok) {
        signed char* xq = (signed char*)d_ws;
        signed char* wq = xq + (size_t)M * DIN;
        float*       xs = (float*)(wq + (size_t)DOUT * DIN);
        rowquant_x<<<M, 256, 0, stream>>>(x, xq, xs, DIN);
        cvt_w_i8<<<2048, 256, 0, stream>>>(w8, (unsigned*)wq, DOUT * DIN / 4);
        hipFuncSetAttribute(reinterpret_cast<const void*>(qlin_gemm_i8),
                            hipFuncAttributeMaxDynamicSharedMemorySize, 65536);
        qlin_gemm_i8<<<nwg, 512, 65536, stream>>>(xq, wq, xs, scale, bias, out,
                                                  M, DOUT, DIN);
    } else {
        dim3 grid((M / FBM) * (DOUT / FBM));
        qlin_gemm_reg<<<grid, 256, 0, stream>>>(x, w8, scale, bias, out, M, DOUT, DIN);
    }
}

// Round 10
// 211.890 us; speedup vs baseline: 13.0321x; 13.0321x over previous
//
#include <hip/hip_runtime.h>
#include <hip/hip_bf16.h>

// ---- int8 path: per-row dynamic quant of x, exact int8 W, i32 MFMA accum ----
#define BM 256
#define BN 256
#define BK 64          // 64 int8 per row per K-tile (2 k-steps of 32)
#define NSLOT 4        // ring of 4 K-tile slots, staged 3 ahead
#define LDS_BYTES (2 * NSLOT * BM * BK)   // 131072 — MUST match launch config

typedef float  f32x4  __attribute__((ext_vector_type(4)));
typedef int    i32x4  __attribute__((ext_vector_type(4)));
typedef int    i32x16 __attribute__((ext_vector_type(16)));
typedef __bf16 bf16x8 __attribute__((ext_vector_type(8)));
typedef __bf16 bf16x4 __attribute__((ext_vector_type(4)));

__device__ __forceinline__ void gload_lds16(const void* g, void* l) {
    __builtin_amdgcn_global_load_lds(
        (const __attribute__((address_space(1))) void*)g,
        (__attribute__((address_space(3))) void*)l, 16, 0, 0);
}

// ------------- prepass 1: per-row absmax quant of x -> int8 + scale ----------
__global__ __launch_bounds__(256)
void rowquant_x(const float* __restrict__ x, signed char* __restrict__ xq,
                float* __restrict__ xs, int K) {
    const int row = blockIdx.x;
    const float* xr = x + (size_t)row * K;
    const int tid = threadIdx.x;
    const int n4 = K / 4;

    float mx = 0.f;
    for (int i = tid; i < n4; i += 256) {
        f32x4 v = ((const f32x4*)xr)[i];
        mx = fmaxf(mx, fmaxf(fmaxf(fabsf(v[0]), fabsf(v[1])),
                             fmaxf(fabsf(v[2]), fabsf(v[3]))));
    }
#pragma unroll
    for (int off = 32; off; off >>= 1)
        mx = fmaxf(mx, __shfl_xor(mx, off));
    __shared__ float smx[4];
    if ((tid & 63) == 0) smx[tid >> 6] = mx;
    __syncthreads();
    mx = fmaxf(fmaxf(smx[0], smx[1]), fmaxf(smx[2], smx[3]));

    const float inv = mx > 0.f ? 127.f / mx : 0.f;
    if (tid == 0) xs[row] = mx / 127.f;

    unsigned* out = (unsigned*)(xq + (size_t)row * K);
    for (int i = tid; i < n4; i += 256) {     // re-read: row is cache-resident
        f32x4 v = ((const f32x4*)xr)[i];
        int q0 = __float2int_rn(v[0] * inv);
        int q1 = __float2int_rn(v[1] * inv);
        int q2 = __float2int_rn(v[2] * inv);
        int q3 = __float2int_rn(v[3] * inv);
        out[i] = (unsigned)(q0 & 255) | ((unsigned)(q1 & 255) << 8) |
                 ((unsigned)(q2 & 255) << 16) | ((unsigned)(q3 & 255) << 24);
    }
}

// ------------- prepass 2: pack W int32 -> int8 (exact) -----------------------
__global__ __launch_bounds__(256)
void cvt_w_i8(const int* __restrict__ w, unsigned* __restrict__ wq, int n4) {
    int i = blockIdx.x * 256 + threadIdx.x;
    const int stride = gridDim.x * 256;
    for (; i < n4; i += stride) {
        i32x4 v = ((const i32x4*)w)[i];
        wq[i] = (unsigned)(v[0] & 255) | ((unsigned)(v[1] & 255) << 8) |
                ((unsigned)(v[2] & 255) << 16) | ((unsigned)(v[3] & 255) << 24);
    }
}

// ------------- main GEMM: i8 32x32x32 MFMA, phase-pipelined ring -------------
// LDS K-tile slot (per operand): [2 k-steps][256 rows][32 B], 16 KiB.
//   phys(kstep,row,half) = kstep*8192 + row*32 + (half ^ ((row>>3)&1))*16
// 2-way bank pattern on ds_read_b128 (free); conflicts measured 0 (R6).
// gload_lds writes linearly; GLOBAL source carries the inverse swizzle.
//
// R10 = R9 schedule with the launch bug fixed (dynamic LDS = 131072, was
// 65536 -> launch silently failed, output stayed zero).
// Schedule per tile t (2 phases, m201-style read-ahead):
//   vmcnt(L1); barrier;              // t staged across all waves
//   read set1=(t,ks1); STAGE_A(t+3); // LDS reads overlap MFMA below
//   8 MFMA on set0=(t,ks0);
//   vmcnt(L2); barrier;              // t+1 staged -> read-ahead safe
//   read set0=(t+1,ks0); STAGE_B(t+3);
//   8 MFMA on set1;
// Ladders (rem = NT-1-t):
//   L1: rem>=2 -> 8, rem==1 -> 4, rem==0 -> 0
//   L2: rem>=3 -> 6, rem==2 -> 4, rem==1 -> 0
// WAR: slot (t+3)&3 == (t-1)&3; its last reads were consumed by MFMAs
// before the tile-t barrier (lgkm drained), STAGE issued after it.

__global__ __launch_bounds__(512, 2)
void qlin_gemm_i8(const signed char* __restrict__ A,  // [M,K] int8 x-quant
                  const signed char* __restrict__ B,  // [N,K] int8 w
                  const float* __restrict__ xs,       // [M] x row scales
                  const float* __restrict__ scale,    // [N]
                  const float* __restrict__ bias,     // [N]
                  float* __restrict__ C, int M, int N, int K) {
    extern __shared__ signed char lds[];
    signed char* lA = lds;                       // [NSLOT][16384]
    signed char* lB = lds + NSLOT * (BM * BK);

    const int NTN = N / BN;
    const int nwg = gridDim.x;
    int bid = blockIdx.x;
    bid = (bid & 7) * (nwg >> 3) + (bid >> 3);   // XCD swizzle (nwg%8==0)
    const int tm = bid / NTN;
    const int tn = bid % NTN;

    const int tid  = threadIdx.x;
    const int lane = tid & 63;
    const int wid  = tid >> 6;     // 0..7
    const int wr   = wid >> 2;     // 0..1  (M half: 128 rows)
    const int wc   = wid & 3;      // 0..3  (N quarter: 64 cols)

    // staging map: lane covers row wid*32 + (lane>>1), physical half lane&1
    const int srow  = wid * 32 + (lane >> 1);
    const int shalf = (lane & 1) ^ ((srow >> 3) & 1);   // logical half (inv swz)
    const signed char* Abase = A + (size_t)(tm * BM + srow) * K + shalf * 16;
    const signed char* Bbase = B + (size_t)(tn * BN + srow) * K + shalf * 16;

    const int NT = K / BK;

    auto STAGE_A = [&](int t) {
        signed char* d = lA + (t & (NSLOT - 1)) * (BM * BK) + wid * 1024;
#pragma unroll
        for (int j = 0; j < 2; ++j)   // j = k-step
            gload_lds16(Abase + t * BK + j * 32, d + j * 8192);
    };
    auto STAGE_B = [&](int t) {
        signed char* d = lB + (t & (NSLOT - 1)) * (BM * BK) + wid * 1024;
#pragma unroll
        for (int j = 0; j < 2; ++j)
            gload_lds16(Bbase + t * BK + j * 32, d + j * 8192);
    };

    const int fr = lane & 31;      // M/N row within 32x32 fragment
    const int fh = lane >> 5;      // k-half selector (16 B)
    const int swz = (fr >> 3) & 1; // row-bit3 slot swizzle
    const int ho = ((fh ^ swz) << 4);

    auto READ_A = [&](const signed char* base, int ks, i32x4* fa) {
        const int o = ks * 8192 + ho;
#pragma unroll
        for (int mi = 0; mi < 4; ++mi) {
            const int R = wr * 128 + mi * 32 + fr;
            fa[mi] = *(const i32x4*)(base + R * 32 + o);
        }
    };
    auto READ_B = [&](const signed char* base, int ks, i32x4* fb) {
        const int o = ks * 8192 + ho;
#pragma unroll
        for (int ni = 0; ni < 2; ++ni) {
            const int R = wc * 64 + ni * 32 + fr;
            fb[ni] = *(const i32x4*)(base + R * 32 + o);
        }
    };

    i32x16 acc[4][2];
#pragma unroll
    for (int mi = 0; mi < 4; ++mi)
#pragma unroll
        for (int ni = 0; ni < 2; ++ni)
#pragma unroll
            for (int r = 0; r < 16; ++r) acc[mi][ni][r] = 0;

    // prologue: stage tiles 0..2; gate tile 0; read set0 = (0, ks0)
    for (int u = 0; u < 3 && u < NT; ++u) { STAGE_A(u); STAGE_B(u); }
    {
        const int pre = NT - 1;
        if (pre >= 2)      asm volatile("s_waitcnt vmcnt(8)" ::: "memory");
        else if (pre == 1) asm volatile("s_waitcnt vmcnt(4)" ::: "memory");
        else               asm volatile("s_waitcnt vmcnt(0)" ::: "memory");
    }
    __builtin_amdgcn_s_barrier();

    i32x4 a0[4], b0[2], a1[4], b1[2];   // set0 (even ks), set1 (odd ks)
    READ_A(lA, 0, a0); READ_B(lB, 0, b0);

    for (int t = 0; t < NT; ++t) {
        const signed char* lAs = lA + (t & (NSLOT - 1)) * (BM * BK);
        const signed char* lBs = lB + (t & (NSLOT - 1)) * (BM * BK);
        const int rem = NT - 1 - t;

        if (t > 0) {
            if (rem >= 2)      asm volatile("s_waitcnt vmcnt(8)" ::: "memory");
            else if (rem == 1) asm volatile("s_waitcnt vmcnt(4)" ::: "memory");
            else               asm volatile("s_waitcnt vmcnt(0)" ::: "memory");
            __builtin_amdgcn_s_barrier();   // tile t staged; set0 holds (t,ks0)
        }

        // phase 0: issue reads of (t,ks1) + stage, then MFMA on set0
        READ_A(lAs, 1, a1); READ_B(lBs, 1, b1);
        if (t + 3 < NT) STAGE_A(t + 3);
        __builtin_amdgcn_s_setprio(1);
#pragma unroll
        for (int mi = 0; mi < 4; ++mi)
#pragma unroll
            for (int ni = 0; ni < 2; ++ni)
                acc[mi][ni] = __builtin_amdgcn_mfma_i32_32x32x32_i8(
                    a0[mi], b0[ni], acc[mi][ni], 0, 0, 0);
        __builtin_amdgcn_s_setprio(0);

        if (rem >= 1) {
            // gate tile t+1 (for the cross-tile read-ahead below)
            if (rem >= 3)      asm volatile("s_waitcnt vmcnt(6)" ::: "memory");
            else if (rem == 2) asm volatile("s_waitcnt vmcnt(4)" ::: "memory");
            else               asm volatile("s_waitcnt vmcnt(0)" ::: "memory");
            __builtin_amdgcn_s_barrier();

            // phase 1: read-ahead (t+1,ks0) + stage, then MFMA on set1
            const signed char* lAn = lA + ((t + 1) & (NSLOT - 1)) * (BM * BK);
            const signed char* lBn = lB + ((t + 1) & (NSLOT - 1)) * (BM * BK);
            READ_A(lAn, 0, a0); READ_B(lBn, 0, b0);
            if (t + 3 < NT) STAGE_B(t + 3);
        }
        __builtin_amdgcn_s_setprio(1);
#pragma unroll
        for (int mi = 0; mi < 4; ++mi)
#pragma unroll
            for (int ni = 0; ni < 2; ++ni)
                acc[mi][ni] = __builtin_amdgcn_mfma_i32_32x32x32_i8(
                    a1[mi], b1[ni], acc[mi][ni], 0, 0, 0);
        __builtin_amdgcn_s_setprio(0);
    }

    // epilogue: 32x32 C/D layout: col = lane&31, row = (r&3)+8*(r>>2)+4*(lane>>5)
    const int rb = tm * BM + wr * 128 + 4 * fh;
    const int cb = tn * BN + wc * 64 + fr;
#pragma unroll
    for (int mi = 0; mi < 4; ++mi) {
        float sm[16];
#pragma unroll
        for (int r = 0; r < 16; ++r)
            sm[r] = xs[rb + mi * 32 + (r & 3) + 8 * (r >> 2)];
#pragma unroll
        for (int ni = 0; ni < 2; ++ni) {
            const int n = cb + ni * 32;
            const float sc = scale[n];
            const float bs = bias[n];
#pragma unroll
            for (int r = 0; r < 16; ++r) {
                const int m = rb + mi * 32 + (r & 3) + 8 * (r >> 2);
                C[(size_t)m * N + n] = fmaf((float)acc[mi][ni][r], sm[r] * sc, bs);
            }
        }
    }
}

// ---------------- fallback (reg-staged 128^2 bf16, any shape) ----------------
#define FBM 128
#define FBK 32

__device__ __forceinline__ int swz_elem(int row, int e) {
    return row * FBK + (e ^ (((row >> 1) & 3) << 3));
}

__global__ __launch_bounds__(256, 2)
void qlin_gemm_reg(const float* __restrict__ A, const int* __restrict__ W,
                   const float* __restrict__ scale, const float* __restrict__ bias,
                   float* __restrict__ C, int M, int N, int K) {
    __shared__ __bf16 lA[2][FBM * FBK];
    __shared__ __bf16 lB[2][FBM * FBK];
    const int NTN = N / FBM;
    const int nwg = gridDim.x;
    int bid = blockIdx.x;
    if ((nwg & 7) == 0) bid = (bid & 7) * (nwg >> 3) + (bid >> 3);
    const int tm = bid / NTN, tn = bid % NTN;
    const int tid = threadIdx.x, lane = tid & 63, wid = tid >> 6;
    const int wr = wid >> 1, wc = wid & 1;
    const int srow0 = tid >> 3, skq = tid & 7;
    const float* aptr = A + (size_t)(tm * FBM + srow0) * K + skq * 4;
    const int*   wptr = W + (size_t)(tn * FBM + srow0) * K + skq * 4;
    const size_t rstride = (size_t)32 * K;
    f32x4 sa[4]; i32x4 sw[4];
    auto LOAD = [&](int t) {
#pragma unroll
        for (int j = 0; j < 4; ++j) {
            sa[j] = *(const f32x4*)(aptr + (size_t)t * FBK + j * rstride);
            sw[j] = *(const i32x4*)(wptr + (size_t)t * FBK + j * rstride);
        }
    };
    auto STORE = [&](int buf) {
#pragma unroll
        for (int j = 0; j < 4; ++j) {
            const int idx = swz_elem(srow0 + j * 32, skq * 4);
            bf16x4 va = { (__bf16)sa[j][0], (__bf16)sa[j][1],
                          (__bf16)sa[j][2], (__bf16)sa[j][3] };
            bf16x4 vw = { (__bf16)(float)sw[j][0], (__bf16)(float)sw[j][1],
                          (__bf16)(float)sw[j][2], (__bf16)(float)sw[j][3] };
            *(bf16x4*)&lA[buf][idx] = va;
            *(bf16x4*)&lB[buf][idx] = vw;
        }
    };
    const f32x4 fzero = {0.f, 0.f, 0.f, 0.f};
    f32x4 acc[4][4];
#pragma unroll
    for (int i = 0; i < 4; ++i)
#pragma unroll
        for (int j = 0; j < 4; ++j) acc[i][j] = fzero;
    const int fr = lane & 15, fks = (lane >> 4) * 8;
    LOAD(0); STORE(0); __syncthreads();
    const int NT = K / FBK;
    for (int t = 0; t < NT; ++t) {
        const int buf = t & 1;
        if (t + 1 < NT) LOAD(t + 1);
        bf16x8 af[4], bfg[4];
#pragma unroll
        for (int mi = 0; mi < 4; ++mi)
            af[mi] = *(const bf16x8*)&lA[buf][swz_elem(wr * 64 + mi * 16 + fr, fks)];
#pragma unroll
        for (int ni = 0; ni < 4; ++ni)
            bfg[ni] = *(const bf16x8*)&lB[buf][swz_elem(wc * 64 + ni * 16 + fr, fks)];
#pragma unroll
        for (int mi = 0; mi < 4; ++mi)
#pragma unroll
            for (int ni = 0; ni < 4; ++ni)
                acc[mi][ni] = __builtin_amdgcn_mfma_f32_16x16x32_bf16(
                    af[mi], bfg[ni], acc[mi][ni], 0, 0, 0);
        if (t + 1 < NT) STORE(buf ^ 1);
        __syncthreads();
    }
    const int row0 = tm * FBM + wr * 64 + (lane >> 4) * 4;
    const int col0 = tn * FBM + wc * 64 + fr;
#pragma unroll
    for (int ni = 0; ni < 4; ++ni) {
        const int n = col0 + ni * 16;
        const float sc = scale[n], bs = bias[n];
#pragma unroll
        for (int mi = 0; mi < 4; ++mi) {
            const int m = row0 + mi * 16;
#pragma unroll
            for (int r = 0; r < 4; ++r)
                C[(size_t)(m + r) * N + n] = fmaf(acc[mi][ni][r], sc, bs);
        }
    }
}

extern "C" void kernel_launch(void* const* d_in, const int* in_sizes, int n_in,
                              void* d_out, int out_size, void* d_ws, size_t ws_size,
                              hipStream_t stream) {
    const float* x     = (const float*)d_in[0];
    const int*   w8    = (const int*)d_in[1];
    const float* scale = (const float*)d_in[2];
    const float* bias  = (const float*)d_in[3];
    float*       out   = (float*)d_out;

    const int DOUT = in_sizes[2];
    const int DIN  = in_sizes[1] / DOUT;
    const int M    = in_sizes[0] / DIN;

    const size_t need = (size_t)M * DIN + (size_t)DOUT * DIN + (size_t)M * 4;
    const int nwg = (M / BM) * (DOUT / BN);
    const bool ok = (ws_size >= need) && (M % BM == 0) && (DOUT % BN == 0) &&
                    (DIN % BK == 0) && (nwg % 8 == 0) && (DIN / BK >= 4);
    if (ok) {
        signed char* xq = (signed char*)d_ws;
        signed char* wq = xq + (size_t)M * DIN;
        float*       xs = (float*)(wq + (size_t)DOUT * DIN);
        rowquant_x<<<M, 256, 0, stream>>>(x, xq, xs, DIN);
        cvt_w_i8<<<2048, 256, 0, stream>>>(w8, (unsigned*)wq, DOUT * DIN / 4);
        hipFuncSetAttribute(reinterpret_cast<const void*>(qlin_gemm_i8),
                            hipFuncAttributeMaxDynamicSharedMemorySize, LDS_BYTES);
        qlin_gemm_i8<<<nwg, 512, LDS_BYTES, stream>>>(xq, wq, xs, scale, bias, out,
                                                      M, DOUT, DIN);
    } else {
        dim3 grid((M / FBM) * (DOUT / FBM));
        qlin_gemm_reg<<<grid, 256, 0, stream>>>(x, w8, scale, bias, out, M, DOUT, DIN);
    }
}

// Round 11
// 209.698 us; speedup vs baseline: 13.1683x; 1.0105x over previous
//
#include <hip/hip_runtime.h>
#include <hip/hip_bf16.h>

// ---- int8 path: per-row dynamic quant of x, exact int8 W, i32 MFMA accum ----
#define BM 256
#define BN 256
#define BK 64          // 64 int8 per row per K-tile (2 k-steps of 32)
#define NSLOT 4        // ring of 4 K-tile slots, staged 3 ahead
#define LDS_BYTES (2 * NSLOT * BM * BK)   // 131072 — MUST match launch config

typedef float  f32x4  __attribute__((ext_vector_type(4)));
typedef int    i32x4  __attribute__((ext_vector_type(4)));
typedef int    i32x16 __attribute__((ext_vector_type(16)));
typedef __bf16 bf16x8 __attribute__((ext_vector_type(8)));
typedef __bf16 bf16x4 __attribute__((ext_vector_type(4)));

__device__ __forceinline__ void gload_lds16(const void* g, void* l) {
    __builtin_amdgcn_global_load_lds(
        (const __attribute__((address_space(1))) void*)g,
        (__attribute__((address_space(3))) void*)l, 16, 0, 0);
}

// ------------- prepass 1: per-row absmax quant of x -> int8 + scale ----------
__global__ __launch_bounds__(256)
void rowquant_x(const float* __restrict__ x, signed char* __restrict__ xq,
                float* __restrict__ xs, int K) {
    const int row = blockIdx.x;
    const float* xr = x + (size_t)row * K;
    const int tid = threadIdx.x;
    const int n4 = K / 4;

    float mx = 0.f;
    for (int i = tid; i < n4; i += 256) {
        f32x4 v = ((const f32x4*)xr)[i];
        mx = fmaxf(mx, fmaxf(fmaxf(fabsf(v[0]), fabsf(v[1])),
                             fmaxf(fabsf(v[2]), fabsf(v[3]))));
    }
#pragma unroll
    for (int off = 32; off; off >>= 1)
        mx = fmaxf(mx, __shfl_xor(mx, off));
    __shared__ float smx[4];
    if ((tid & 63) == 0) smx[tid >> 6] = mx;
    __syncthreads();
    mx = fmaxf(fmaxf(smx[0], smx[1]), fmaxf(smx[2], smx[3]));

    const float inv = mx > 0.f ? 127.f / mx : 0.f;
    if (tid == 0) xs[row] = mx / 127.f;

    unsigned* out = (unsigned*)(xq + (size_t)row * K);
    for (int i = tid; i < n4; i += 256) {     // re-read: row is cache-resident
        f32x4 v = ((const f32x4*)xr)[i];
        int q0 = __float2int_rn(v[0] * inv);
        int q1 = __float2int_rn(v[1] * inv);
        int q2 = __float2int_rn(v[2] * inv);
        int q3 = __float2int_rn(v[3] * inv);
        out[i] = (unsigned)(q0 & 255) | ((unsigned)(q1 & 255) << 8) |
                 ((unsigned)(q2 & 255) << 16) | ((unsigned)(q3 & 255) << 24);
    }
}

// ------------- prepass 2: pack W int32 -> int8 (exact) -----------------------
__global__ __launch_bounds__(256)
void cvt_w_i8(const int* __restrict__ w, unsigned* __restrict__ wq, int n4) {
    int i = blockIdx.x * 256 + threadIdx.x;
    const int stride = gridDim.x * 256;
    for (; i < n4; i += stride) {
        i32x4 v = ((const i32x4*)w)[i];
        wq[i] = (unsigned)(v[0] & 255) | ((unsigned)(v[1] & 255) << 8) |
                ((unsigned)(v[2] & 255) << 16) | ((unsigned)(v[3] & 255) << 24);
    }
}

// ------------- main GEMM: i8 32x32x32 MFMA, WAVE-STAGGERED anti-phase --------
// LDS K-tile slot (per operand): [2 k-steps][256 rows][32 B], 16 KiB.
//   phys(kstep,row,half) = kstep*8192 + row*32 + (half ^ ((row>>3)&1))*16
// gload_lds writes linearly; GLOBAL source carries the inverse swizzle.
//
// R11 insight: R6/R7/R10 (three intra-wave schedules) all hit 3000 cy/tile,
// MfmaUtil 39% — the barrier phase-locks ALL waves: everyone reads together
// (LDS pipe ~1150 cy, matrix idle) then MFMAs together (matrix ~1170 cy, LDS
// idle). Fix: per-wave role stagger, legal because acc is k-commutative.
//   even waves: [bar] READ(ks0) MFMA READ(ks1) MFMA
//   odd  waves: [bar] MFMA(pending regs from prev tile) READ(ks0) READ(ks1)
//               MFMA(ks0); pending <- ks1
// -> at any instant half the waves use LDS, half the matrix pipe.
// Safety: uniform lgkmcnt(0) before each barrier => odds' cross-barrier
// register carry is complete before any wave's re-STAGE of that slot can
// be issued (STAGE(t+3) hits slot (t-1)&3, issued only after barrier t).
// vmcnt ladder (rem = NT-1-t): rem>=2 -> 8, rem==1 -> 4, rem==0 -> 0
// (4 own loads per tile, tiles t+1..t+2 in flight at barrier t).

__global__ __launch_bounds__(512, 2)
void qlin_gemm_i8(const signed char* __restrict__ A,  // [M,K] int8 x-quant
                  const signed char* __restrict__ B,  // [N,K] int8 w
                  const float* __restrict__ xs,       // [M] x row scales
                  const float* __restrict__ scale,    // [N]
                  const float* __restrict__ bias,     // [N]
                  float* __restrict__ C, int M, int N, int K) {
    extern __shared__ signed char lds[];
    signed char* lA = lds;                       // [NSLOT][16384]
    signed char* lB = lds + NSLOT * (BM * BK);

    const int NTN = N / BN;
    const int nwg = gridDim.x;
    int bid = blockIdx.x;
    bid = (bid & 7) * (nwg >> 3) + (bid >> 3);   // XCD swizzle (nwg%8==0)
    const int tm = bid / NTN;
    const int tn = bid % NTN;

    const int tid  = threadIdx.x;
    const int lane = tid & 63;
    const int wid  = tid >> 6;     // 0..7
    const int wr   = wid >> 2;     // 0..1  (M half: 128 rows)
    const int wc   = wid & 3;      // 0..3  (N quarter: 64 cols)
    const bool odd = (wid & 1) != 0;   // wave-uniform role

    // staging map: lane covers row wid*32 + (lane>>1), physical half lane&1
    const int srow  = wid * 32 + (lane >> 1);
    const int shalf = (lane & 1) ^ ((srow >> 3) & 1);   // logical half (inv swz)
    const signed char* Abase = A + (size_t)(tm * BM + srow) * K + shalf * 16;
    const signed char* Bbase = B + (size_t)(tn * BN + srow) * K + shalf * 16;

    const int NT = K / BK;

    auto STAGE_A = [&](int t) {
        signed char* d = lA + (t & (NSLOT - 1)) * (BM * BK) + wid * 1024;
#pragma unroll
        for (int j = 0; j < 2; ++j)   // j = k-step
            gload_lds16(Abase + t * BK + j * 32, d + j * 8192);
    };
    auto STAGE_B = [&](int t) {
        signed char* d = lB + (t & (NSLOT - 1)) * (BM * BK) + wid * 1024;
#pragma unroll
        for (int j = 0; j < 2; ++j)
            gload_lds16(Bbase + t * BK + j * 32, d + j * 8192);
    };

    const int fr = lane & 31;      // M/N row within 32x32 fragment
    const int fh = lane >> 5;      // k-half selector (16 B)
    const int swz = (fr >> 3) & 1; // row-bit3 slot swizzle
    const int ho = ((fh ^ swz) << 4);

    auto READ_A = [&](const signed char* base, int ks, i32x4* fa) {
        const int o = ks * 8192 + ho;
#pragma unroll
        for (int mi = 0; mi < 4; ++mi) {
            const int R = wr * 128 + mi * 32 + fr;
            fa[mi] = *(const i32x4*)(base + R * 32 + o);
        }
    };
    auto READ_B = [&](const signed char* base, int ks, i32x4* fb) {
        const int o = ks * 8192 + ho;
#pragma unroll
        for (int ni = 0; ni < 2; ++ni) {
            const int R = wc * 64 + ni * 32 + fr;
            fb[ni] = *(const i32x4*)(base + R * 32 + o);
        }
    };

    i32x16 acc[4][2];
#pragma unroll
    for (int mi = 0; mi < 4; ++mi)
#pragma unroll
        for (int ni = 0; ni < 2; ++ni)
#pragma unroll
            for (int r = 0; r < 16; ++r) acc[mi][ni][r] = 0;

    auto MFMA8 = [&](const i32x4* fa, const i32x4* fb) {
        __builtin_amdgcn_s_setprio(1);
#pragma unroll
        for (int mi = 0; mi < 4; ++mi)
#pragma unroll
            for (int ni = 0; ni < 2; ++ni)
                acc[mi][ni] = __builtin_amdgcn_mfma_i32_32x32x32_i8(
                    fa[mi], fb[ni], acc[mi][ni], 0, 0, 0);
        __builtin_amdgcn_s_setprio(0);
    };

    // prologue: stage tiles 0..2 (no barrier here; loop top gates tile 0)
    for (int u = 0; u < 3 && u < NT; ++u) { STAGE_A(u); STAGE_B(u); }

    i32x4 a0[4], b0[2], a1[4], b1[2];   // a1/b1 = odd waves' pending set

    for (int t = 0; t < NT; ++t) {
        const signed char* lAs = lA + (t & (NSLOT - 1)) * (BM * BK);
        const signed char* lBs = lB + (t & (NSLOT - 1)) * (BM * BK);
        const int rem = NT - 1 - t;

        // uniform sync point: all prior ds_reads drained (cross-barrier
        // register carry is then WAR-safe), tile t staged (vmcnt ladder)
        asm volatile("s_waitcnt lgkmcnt(0)" ::: "memory");
        if (rem >= 2)      asm volatile("s_waitcnt vmcnt(8)" ::: "memory");
        else if (rem == 1) asm volatile("s_waitcnt vmcnt(4)" ::: "memory");
        else               asm volatile("s_waitcnt vmcnt(0)" ::: "memory");
        __builtin_amdgcn_s_barrier();

        if (!odd) {
            // even waves: read-first
            READ_A(lAs, 0, a0); READ_B(lBs, 0, b0);
            if (t + 3 < NT) STAGE_A(t + 3);
            MFMA8(a0, b0);
            READ_A(lAs, 1, a0); READ_B(lBs, 1, b0);
            if (t + 3 < NT) STAGE_B(t + 3);
            MFMA8(a0, b0);
        } else {
            // odd waves: MFMA-first on pending regs (k-order commutes)
            if (t > 0) MFMA8(a1, b1);
            if (t + 3 < NT) STAGE_A(t + 3);
            READ_A(lAs, 0, a0); READ_B(lBs, 0, b0);
            READ_A(lAs, 1, a1); READ_B(lBs, 1, b1);   // pending for t+1
            if (t + 3 < NT) STAGE_B(t + 3);
            MFMA8(a0, b0);
        }
    }
    if (odd) MFMA8(a1, b1);   // flush pending (NT-1, ks1)

    // epilogue: 32x32 C/D layout: col = lane&31, row = (r&3)+8*(r>>2)+4*(lane>>5)
    const int rb = tm * BM + wr * 128 + 4 * fh;
    const int cb = tn * BN + wc * 64 + fr;
#pragma unroll
    for (int mi = 0; mi < 4; ++mi) {
        float sm[16];
#pragma unroll
        for (int r = 0; r < 16; ++r)
            sm[r] = xs[rb + mi * 32 + (r & 3) + 8 * (r >> 2)];
#pragma unroll
        for (int ni = 0; ni < 2; ++ni) {
            const int n = cb + ni * 32;
            const float sc = scale[n];
            const float bs = bias[n];
#pragma unroll
            for (int r = 0; r < 16; ++r) {
                const int m = rb + mi * 32 + (r & 3) + 8 * (r >> 2);
                C[(size_t)m * N + n] = fmaf((float)acc[mi][ni][r], sm[r] * sc, bs);
            }
        }
    }
}

// ---------------- fallback (reg-staged 128^2 bf16, any shape) ----------------
#define FBM 128
#define FBK 32

__device__ __forceinline__ int swz_elem(int row, int e) {
    return row * FBK + (e ^ (((row >> 1) & 3) << 3));
}

__global__ __launch_bounds__(256, 2)
void qlin_gemm_reg(const float* __restrict__ A, const int* __restrict__ W,
                   const float* __restrict__ scale, const float* __restrict__ bias,
                   float* __restrict__ C, int M, int N, int K) {
    __shared__ __bf16 lA[2][FBM * FBK];
    __shared__ __bf16 lB[2][FBM * FBK];
    const int NTN = N / FBM;
    const int nwg = gridDim.x;
    int bid = blockIdx.x;
    if ((nwg & 7) == 0) bid = (bid & 7) * (nwg >> 3) + (bid >> 3);
    const int tm = bid / NTN, tn = bid % NTN;
    const int tid = threadIdx.x, lane = tid & 63, wid = tid >> 6;
    const int wr = wid >> 1, wc = wid & 1;
    const int srow0 = tid >> 3, skq = tid & 7;
    const float* aptr = A + (size_t)(tm * FBM + srow0) * K + skq * 4;
    const int*   wptr = W + (size_t)(tn * FBM + srow0) * K + skq * 4;
    const size_t rstride = (size_t)32 * K;
    f32x4 sa[4]; i32x4 sw[4];
    auto LOAD = [&](int t) {
#pragma unroll
        for (int j = 0; j < 4; ++j) {
            sa[j] = *(const f32x4*)(aptr + (size_t)t * FBK + j * rstride);
            sw[j] = *(const i32x4*)(wptr + (size_t)t * FBK + j * rstride);
        }
    };
    auto STORE = [&](int buf) {
#pragma unroll
        for (int j = 0; j < 4; ++j) {
            const int idx = swz_elem(srow0 + j * 32, skq * 4);
            bf16x4 va = { (__bf16)sa[j][0], (__bf16)sa[j][1],
                          (__bf16)sa[j][2], (__bf16)sa[j][3] };
            bf16x4 vw = { (__bf16)(float)sw[j][0], (__bf16)(float)sw[j][1],
                          (__bf16)(float)sw[j][2], (__bf16)(float)sw[j][3] };
            *(bf16x4*)&lA[buf][idx] = va;
            *(bf16x4*)&lB[buf][idx] = vw;
        }
    };
    const f32x4 fzero = {0.f, 0.f, 0.f, 0.f};
    f32x4 acc[4][4];
#pragma unroll
    for (int i = 0; i < 4; ++i)
#pragma unroll
        for (int j = 0; j < 4; ++j) acc[i][j] = fzero;
    const int fr = lane & 15, fks = (lane >> 4) * 8;
    LOAD(0); STORE(0); __syncthreads();
    const int NT = K / FBK;
    for (int t = 0; t < NT; ++t) {
        const int buf = t & 1;
        if (t + 1 < NT) LOAD(t + 1);
        bf16x8 af[4], bfg[4];
#pragma unroll
        for (int mi = 0; mi < 4; ++mi)
            af[mi] = *(const bf16x8*)&lA[buf][swz_elem(wr * 64 + mi * 16 + fr, fks)];
#pragma unroll
        for (int ni = 0; ni < 4; ++ni)
            bfg[ni] = *(const bf16x8*)&lB[buf][swz_elem(wc * 64 + ni * 16 + fr, fks)];
#pragma unroll
        for (int mi = 0; mi < 4; ++mi)
#pragma unroll
            for (int ni = 0; ni < 4; ++ni)
                acc[mi][ni] = __builtin_amdgcn_mfma_f32_16x16x32_bf16(
                    af[mi], bfg[ni], acc[mi][ni], 0, 0, 0);
        if (t + 1 < NT) STORE(buf ^ 1);
        __syncthreads();
    }
    const int row0 = tm * FBM + wr * 64 + (lane >> 4) * 4;
    const int col0 = tn * FBM + wc * 64 + fr;
#pragma unroll
    for (int ni = 0; ni < 4; ++ni) {
        const int n = col0 + ni * 16;
        const float sc = scale[n], bs = bias[n];
#pragma unroll
        for (int mi = 0; mi < 4; ++mi) {
            const int m = row0 + mi * 16;
#pragma unroll
            for (int r = 0; r < 4; ++r)
                C[(size_t)(m + r) * N + n] = fmaf(acc[mi][ni][r], sc, bs);
        }
    }
}

extern "C" void kernel_launch(void* const* d_in, const int* in_sizes, int n_in,
                              void* d_out, int out_size, void* d_ws, size_t ws_size,
                              hipStream_t stream) {
    const float* x     = (const float*)d_in[0];
    const int*   w8    = (const int*)d_in[1];
    const float* scale = (const float*)d_in[2];
    const float* bias  = (const float*)d_in[3];
    float*       out   = (float*)d_out;

    const int DOUT = in_sizes[2];
    const int DIN  = in_sizes[1] / DOUT;
    const int M    = in_sizes[0] / DIN;

    const size_t need = (size_t)M * DIN + (size_t)DOUT * DIN + (size_t)M * 4;
    const int nwg = (M / BM) * (DOUT / BN);
    const bool ok = (ws_size >= need) && (M % BM == 0) && (DOUT % BN == 0) &&
                    (DIN % BK == 0) && (nwg % 8 == 0) && (DIN / BK >= 4);
    if (ok) {
        signed char* xq = (signed char*)d_ws;
        signed char* wq = xq + (size_t)M * DIN;
        float*       xs = (float*)(wq + (size_t)DOUT * DIN);
        rowquant_x<<<M, 256, 0, stream>>>(x, xq, xs, DIN);
        cvt_w_i8<<<2048, 256, 0, stream>>>(w8, (unsigned*)wq, DOUT * DIN / 4);
        hipFuncSetAttribute(reinterpret_cast<const void*>(qlin_gemm_i8),
                            hipFuncAttributeMaxDynamicSharedMemorySize, LDS_BYTES);
        qlin_gemm_i8<<<nwg, 512, LDS_BYTES, stream>>>(xq, wq, xs, scale, bias, out,
                                                      M, DOUT, DIN);
    } else {
        dim3 grid((M / FBM) * (DOUT / FBM));
        qlin_gemm_reg<<<grid, 256, 0, stream>>>(x, w8, scale, bias, out, M, DOUT, DIN);
    }
}

// Round 12
// 208.152 us; speedup vs baseline: 13.2661x; 1.0074x over previous
//
#include <hip/hip_runtime.h>
#include <hip/hip_bf16.h>

// ---- int8 path: per-row dynamic quant of x, exact int8 W, i32 MFMA accum ----
#define BM 256
#define BN 256
#define BK 64          // 64 int8 per row per K-tile (2 k-steps of 32)
#define NSLOT 4        // ring of 4 K-tile slots, staged 3 ahead
#define LDS_BYTES (2 * NSLOT * BM * BK)   // 131072 — MUST match launch config

typedef float  f32x4  __attribute__((ext_vector_type(4)));
typedef int    i32x4  __attribute__((ext_vector_type(4)));
typedef int    i32x16 __attribute__((ext_vector_type(16)));
typedef __bf16 bf16x8 __attribute__((ext_vector_type(8)));
typedef __bf16 bf16x4 __attribute__((ext_vector_type(4)));

__device__ __forceinline__ void gload_lds16(const void* g, void* l) {
    __builtin_amdgcn_global_load_lds(
        (const __attribute__((address_space(1))) void*)g,
        (__attribute__((address_space(3))) void*)l, 16, 0, 0);
}

// ------------- prepass 1: per-row absmax quant of x -> int8 + scale ----------
__global__ __launch_bounds__(256)
void rowquant_x(const float* __restrict__ x, signed char* __restrict__ xq,
                float* __restrict__ xs, int K) {
    const int row = blockIdx.x;
    const float* xr = x + (size_t)row * K;
    const int tid = threadIdx.x;
    const int n4 = K / 4;

    float mx = 0.f;
    for (int i = tid; i < n4; i += 256) {
        f32x4 v = ((const f32x4*)xr)[i];
        mx = fmaxf(mx, fmaxf(fmaxf(fabsf(v[0]), fabsf(v[1])),
                             fmaxf(fabsf(v[2]), fabsf(v[3]))));
    }
#pragma unroll
    for (int off = 32; off; off >>= 1)
        mx = fmaxf(mx, __shfl_xor(mx, off));
    __shared__ float smx[4];
    if ((tid & 63) == 0) smx[tid >> 6] = mx;
    __syncthreads();
    mx = fmaxf(fmaxf(smx[0], smx[1]), fmaxf(smx[2], smx[3]));

    const float inv = mx > 0.f ? 127.f / mx : 0.f;
    if (tid == 0) xs[row] = mx / 127.f;

    unsigned* out = (unsigned*)(xq + (size_t)row * K);
    for (int i = tid; i < n4; i += 256) {     // re-read: row is cache-resident
        f32x4 v = ((const f32x4*)xr)[i];
        int q0 = __float2int_rn(v[0] * inv);
        int q1 = __float2int_rn(v[1] * inv);
        int q2 = __float2int_rn(v[2] * inv);
        int q3 = __float2int_rn(v[3] * inv);
        out[i] = (unsigned)(q0 & 255) | ((unsigned)(q1 & 255) << 8) |
                 ((unsigned)(q2 & 255) << 16) | ((unsigned)(q3 & 255) << 24);
    }
}

// ------------- prepass 2: pack W int32 -> int8 (exact) -----------------------
__global__ __launch_bounds__(256)
void cvt_w_i8(const int* __restrict__ w, unsigned* __restrict__ wq, int n4) {
    int i = blockIdx.x * 256 + threadIdx.x;
    const int stride = gridDim.x * 256;
    for (; i < n4; i += stride) {
        i32x4 v = ((const i32x4*)w)[i];
        wq[i] = (unsigned)(v[0] & 255) | ((unsigned)(v[1] & 255) << 8) |
                ((unsigned)(v[2] & 255) << 16) | ((unsigned)(v[3] & 255) << 24);
    }
}

// ------------- main GEMM: i8 32x32x32 MFMA, PER-SIMD wave stagger ------------
// LDS K-tile slot (per operand): [2 k-steps][256 rows][32 B], 16 KiB.
//   phys(kstep,row,half) = kstep*8192 + row*32 + (half ^ ((row>>3)&1))*16
// gload_lds writes linearly; GLOBAL source carries the inverse swizzle.
//
// R12 fix of R11: matrix units are PER-SIMD and wave->SIMD = wid % 4, so a
// role split by (wid & 1) put both waves of each SIMD in the SAME role
// (SIMD0 holds waves {0,4}) -> no intra-SIMD overlap, unchanged 39%.
// Correct split: role = (wid >> 2) & 1 -> each SIMD holds {read-first,
// MFMA-first}. While the MFMA-first wave blocks in its 8-MFMA cluster
// (~293 cy on the SIMD matrix unit), the partner wave issues its ds_reads
// (CU LDS unit), then they hand off -> matrix unit continuously fed.
//   read-first (lo): [bar] R(ks0) M(ks0) R(ks1) M(ks1)
//   mfma-first (hi): [bar] M(pending) R(ks0) R(ks1) M(ks0); pending <- ks1
// Legal: acc is k-commutative. Uniform lgkmcnt(0)+vmcnt+barrier per tile;
// pending regs are WAR-safe (drained before barrier; STAGE(t+3) hits slot
// (t-1)&3, issued only after barrier t).
// vmcnt ladder (rem = NT-1-t): rem>=2 -> 8, rem==1 -> 4, rem==0 -> 0.

__global__ __launch_bounds__(512, 2)
void qlin_gemm_i8(const signed char* __restrict__ A,  // [M,K] int8 x-quant
                  const signed char* __restrict__ B,  // [N,K] int8 w
                  const float* __restrict__ xs,       // [M] x row scales
                  const float* __restrict__ scale,    // [N]
                  const float* __restrict__ bias,     // [N]
                  float* __restrict__ C, int M, int N, int K) {
    extern __shared__ signed char lds[];
    signed char* lA = lds;                       // [NSLOT][16384]
    signed char* lB = lds + NSLOT * (BM * BK);

    const int NTN = N / BN;
    const int nwg = gridDim.x;
    int bid = blockIdx.x;
    bid = (bid & 7) * (nwg >> 3) + (bid >> 3);   // XCD swizzle (nwg%8==0)
    const int tm = bid / NTN;
    const int tn = bid % NTN;

    const int tid  = threadIdx.x;
    const int lane = tid & 63;
    const int wid  = tid >> 6;     // 0..7
    const int wr   = wid >> 2;     // 0..1  (M half: 128 rows)
    const int wc   = wid & 3;      // 0..3  (N quarter: 64 cols)
    const bool hi  = ((wid >> 2) & 1) != 0;   // role: one of each per SIMD

    // staging map: lane covers row wid*32 + (lane>>1), physical half lane&1
    const int srow  = wid * 32 + (lane >> 1);
    const int shalf = (lane & 1) ^ ((srow >> 3) & 1);   // logical half (inv swz)
    const signed char* Abase = A + (size_t)(tm * BM + srow) * K + shalf * 16;
    const signed char* Bbase = B + (size_t)(tn * BN + srow) * K + shalf * 16;

    const int NT = K / BK;

    auto STAGE_A = [&](int t) {
        signed char* d = lA + (t & (NSLOT - 1)) * (BM * BK) + wid * 1024;
#pragma unroll
        for (int j = 0; j < 2; ++j)   // j = k-step
            gload_lds16(Abase + t * BK + j * 32, d + j * 8192);
    };
    auto STAGE_B = [&](int t) {
        signed char* d = lB + (t & (NSLOT - 1)) * (BM * BK) + wid * 1024;
#pragma unroll
        for (int j = 0; j < 2; ++j)
            gload_lds16(Bbase + t * BK + j * 32, d + j * 8192);
    };

    const int fr = lane & 31;      // M/N row within 32x32 fragment
    const int fh = lane >> 5;      // k-half selector (16 B)
    const int swz = (fr >> 3) & 1; // row-bit3 slot swizzle
    const int ho = ((fh ^ swz) << 4);

    auto READ_A = [&](const signed char* base, int ks, i32x4* fa) {
        const int o = ks * 8192 + ho;
#pragma unroll
        for (int mi = 0; mi < 4; ++mi) {
            const int R = wr * 128 + mi * 32 + fr;
            fa[mi] = *(const i32x4*)(base + R * 32 + o);
        }
    };
    auto READ_B = [&](const signed char* base, int ks, i32x4* fb) {
        const int o = ks * 8192 + ho;
#pragma unroll
        for (int ni = 0; ni < 2; ++ni) {
            const int R = wc * 64 + ni * 32 + fr;
            fb[ni] = *(const i32x4*)(base + R * 32 + o);
        }
    };

    i32x16 acc[4][2];
#pragma unroll
    for (int mi = 0; mi < 4; ++mi)
#pragma unroll
        for (int ni = 0; ni < 2; ++ni)
#pragma unroll
            for (int r = 0; r < 16; ++r) acc[mi][ni][r] = 0;

    auto MFMA8 = [&](const i32x4* fa, const i32x4* fb) {
        __builtin_amdgcn_s_setprio(1);
#pragma unroll
        for (int mi = 0; mi < 4; ++mi)
#pragma unroll
            for (int ni = 0; ni < 2; ++ni)
                acc[mi][ni] = __builtin_amdgcn_mfma_i32_32x32x32_i8(
                    fa[mi], fb[ni], acc[mi][ni], 0, 0, 0);
        __builtin_amdgcn_s_setprio(0);
    };

    // prologue: stage tiles 0..2 (no barrier here; loop top gates tile 0)
    for (int u = 0; u < 3 && u < NT; ++u) { STAGE_A(u); STAGE_B(u); }

    i32x4 a0[4], b0[2], a1[4], b1[2];   // a1/b1 = hi waves' pending set

    for (int t = 0; t < NT; ++t) {
        const signed char* lAs = lA + (t & (NSLOT - 1)) * (BM * BK);
        const signed char* lBs = lB + (t & (NSLOT - 1)) * (BM * BK);
        const int rem = NT - 1 - t;

        // uniform sync point: all prior ds_reads drained (cross-barrier
        // register carry is then WAR-safe), tile t staged (vmcnt ladder)
        asm volatile("s_waitcnt lgkmcnt(0)" ::: "memory");
        if (rem >= 2)      asm volatile("s_waitcnt vmcnt(8)" ::: "memory");
        else if (rem == 1) asm volatile("s_waitcnt vmcnt(4)" ::: "memory");
        else               asm volatile("s_waitcnt vmcnt(0)" ::: "memory");
        __builtin_amdgcn_s_barrier();

        if (!hi) {
            // read-first waves (SIMD partner is MFMA-first)
            READ_A(lAs, 0, a0); READ_B(lBs, 0, b0);
            if (t + 3 < NT) STAGE_A(t + 3);
            MFMA8(a0, b0);
            READ_A(lAs, 1, a0); READ_B(lBs, 1, b0);
            if (t + 3 < NT) STAGE_B(t + 3);
            MFMA8(a0, b0);
        } else {
            // MFMA-first waves: run pending cluster while partner reads
            if (t > 0) MFMA8(a1, b1);
            if (t + 3 < NT) STAGE_A(t + 3);
            READ_A(lAs, 0, a0); READ_B(lBs, 0, b0);
            READ_A(lAs, 1, a1); READ_B(lBs, 1, b1);   // pending for t+1
            if (t + 3 < NT) STAGE_B(t + 3);
            MFMA8(a0, b0);
        }
    }
    if (hi) MFMA8(a1, b1);   // flush pending (NT-1, ks1)

    // epilogue: 32x32 C/D layout: col = lane&31, row = (r&3)+8*(r>>2)+4*(lane>>5)
    const int rb = tm * BM + wr * 128 + 4 * fh;
    const int cb = tn * BN + wc * 64 + fr;
#pragma unroll
    for (int mi = 0; mi < 4; ++mi) {
        float sm[16];
#pragma unroll
        for (int r = 0; r < 16; ++r)
            sm[r] = xs[rb + mi * 32 + (r & 3) + 8 * (r >> 2)];
#pragma unroll
        for (int ni = 0; ni < 2; ++ni) {
            const int n = cb + ni * 32;
            const float sc = scale[n];
            const float bs = bias[n];
#pragma unroll
            for (int r = 0; r < 16; ++r) {
                const int m = rb + mi * 32 + (r & 3) + 8 * (r >> 2);
                C[(size_t)m * N + n] = fmaf((float)acc[mi][ni][r], sm[r] * sc, bs);
            }
        }
    }
}

// ---------------- fallback (reg-staged 128^2 bf16, any shape) ----------------
#define FBM 128
#define FBK 32

__device__ __forceinline__ int swz_elem(int row, int e) {
    return row * FBK + (e ^ (((row >> 1) & 3) << 3));
}

__global__ __launch_bounds__(256, 2)
void qlin_gemm_reg(const float* __restrict__ A, const int* __restrict__ W,
                   const float* __restrict__ scale, const float* __restrict__ bias,
                   float* __restrict__ C, int M, int N, int K) {
    __shared__ __bf16 lA[2][FBM * FBK];
    __shared__ __bf16 lB[2][FBM * FBK];
    const int NTN = N / FBM;
    const int nwg = gridDim.x;
    int bid = blockIdx.x;
    if ((nwg & 7) == 0) bid = (bid & 7) * (nwg >> 3) + (bid >> 3);
    const int tm = bid / NTN, tn = bid % NTN;
    const int tid = threadIdx.x, lane = tid & 63, wid = tid >> 6;
    const int wr = wid >> 1, wc = wid & 1;
    const int srow0 = tid >> 3, skq = tid & 7;
    const float* aptr = A + (size_t)(tm * FBM + srow0) * K + skq * 4;
    const int*   wptr = W + (size_t)(tn * FBM + srow0) * K + skq * 4;
    const size_t rstride = (size_t)32 * K;
    f32x4 sa[4]; i32x4 sw[4];
    auto LOAD = [&](int t) {
#pragma unroll
        for (int j = 0; j < 4; ++j) {
            sa[j] = *(const f32x4*)(aptr + (size_t)t * FBK + j * rstride);
            sw[j] = *(const i32x4*)(wptr + (size_t)t * FBK + j * rstride);
        }
    };
    auto STORE = [&](int buf) {
#pragma unroll
        for (int j = 0; j < 4; ++j) {
            const int idx = swz_elem(srow0 + j * 32, skq * 4);
            bf16x4 va = { (__bf16)sa[j][0], (__bf16)sa[j][1],
                          (__bf16)sa[j][2], (__bf16)sa[j][3] };
            bf16x4 vw = { (__bf16)(float)sw[j][0], (__bf16)(float)sw[j][1],
                          (__bf16)(float)sw[j][2], (__bf16)(float)sw[j][3] };
            *(bf16x4*)&lA[buf][idx] = va;
            *(bf16x4*)&lB[buf][idx] = vw;
        }
    };
    const f32x4 fzero = {0.f, 0.f, 0.f, 0.f};
    f32x4 acc[4][4];
#pragma unroll
    for (int i = 0; i < 4; ++i)
#pragma unroll
        for (int j = 0; j < 4; ++j) acc[i][j] = fzero;
    const int fr = lane & 15, fks = (lane >> 4) * 8;
    LOAD(0); STORE(0); __syncthreads();
    const int NT = K / FBK;
    for (int t = 0; t < NT; ++t) {
        const int buf = t & 1;
        if (t + 1 < NT) LOAD(t + 1);
        bf16x8 af[4], bfg[4];
#pragma unroll
        for (int mi = 0; mi < 4; ++mi)
            af[mi] = *(const bf16x8*)&lA[buf][swz_elem(wr * 64 + mi * 16 + fr, fks)];
#pragma unroll
        for (int ni = 0; ni < 4; ++ni)
            bfg[ni] = *(const bf16x8*)&lB[buf][swz_elem(wc * 64 + ni * 16 + fr, fks)];
#pragma unroll
        for (int mi = 0; mi < 4; ++mi)
#pragma unroll
            for (int ni = 0; ni < 4; ++ni)
                acc[mi][ni] = __builtin_amdgcn_mfma_f32_16x16x32_bf16(
                    af[mi], bfg[ni], acc[mi][ni], 0, 0, 0);
        if (t + 1 < NT) STORE(buf ^ 1);
        __syncthreads();
    }
    const int row0 = tm * FBM + wr * 64 + (lane >> 4) * 4;
    const int col0 = tn * FBM + wc * 64 + fr;
#pragma unroll
    for (int ni = 0; ni < 4; ++ni) {
        const int n = col0 + ni * 16;
        const float sc = scale[n], bs = bias[n];
#pragma unroll
        for (int mi = 0; mi < 4; ++mi) {
            const int m = row0 + mi * 16;
#pragma unroll
            for (int r = 0; r < 4; ++r)
                C[(size_t)(m + r) * N + n] = fmaf(acc[mi][ni][r], sc, bs);
        }
    }
}

extern "C" void kernel_launch(void* const* d_in, const int* in_sizes, int n_in,
                              void* d_out, int out_size, void* d_ws, size_t ws_size,
                              hipStream_t stream) {
    const float* x     = (const float*)d_in[0];
    const int*   w8    = (const int*)d_in[1];
    const float* scale = (const float*)d_in[2];
    const float* bias  = (const float*)d_in[3];
    float*       out   = (float*)d_out;

    const int DOUT = in_sizes[2];
    const int DIN  = in_sizes[1] / DOUT;
    const int M    = in_sizes[0] / DIN;

    const size_t need = (size_t)M * DIN + (size_t)DOUT * DIN + (size_t)M * 4;
    const int nwg = (M / BM) * (DOUT / BN);
    const bool ok = (ws_size >= need) && (M % BM == 0) && (DOUT % BN == 0) &&
                    (DIN % BK == 0) && (nwg % 8 == 0) && (DIN / BK >= 4);
    if (ok) {
        signed char* xq = (signed char*)d_ws;
        signed char* wq = xq + (size_t)M * DIN;
        float*       xs = (float*)(wq + (size_t)DOUT * DIN);
        rowquant_x<<<M, 256, 0, stream>>>(x, xq, xs, DIN);
        cvt_w_i8<<<2048, 256, 0, stream>>>(w8, (unsigned*)wq, DOUT * DIN / 4);
        hipFuncSetAttribute(reinterpret_cast<const void*>(qlin_gemm_i8),
                            hipFuncAttributeMaxDynamicSharedMemorySize, LDS_BYTES);
        qlin_gemm_i8<<<nwg, 512, LDS_BYTES, stream>>>(xq, wq, xs, scale, bias, out,
                                                      M, DOUT, DIN);
    } else {
        dim3 grid((M / FBM) * (DOUT / FBM));
        qlin_gemm_reg<<<grid, 256, 0, stream>>>(x, w8, scale, bias, out, M, DOUT, DIN);
    }
}